// Round 17
// baseline (534.980 us; speedup 1.0000x reference)
//
#include <hip/hip_runtime.h>
#include <hip/hip_fp16.h>

#define F_IN 1433
#define BCAP 96        // bucket capacity; deg ~ Poisson(32), P(>96) ~ 1e-18
#define WSTR 2048      // wt row stride in halfs (global, L2-resident)
#define XSTR 1448      // LDS x-panel row stride in halfs: 2896B, %16=0, 2-way banks (free)

// edge_index int32: src = ei[0:E], dst = ei[E:2E]

typedef _Float16 f16x8 __attribute__((ext_vector_type(8)));
typedef float    f32x4 __attribute__((ext_vector_type(4)));

// zero cnt + build fp16 W^T table (wt[c][k], zero-padded) in one node
__global__ __launch_bounds__(256) void k_prep(const float* __restrict__ W1,
    int* __restrict__ cnt, _Float16* __restrict__ wt, int N)
{
    int i = blockIdx.x * 256 + threadIdx.x;
    if (i < N) cnt[i] = 0;
    if (i < 16 * WSTR) {
        int c = i >> 11, k = i & (WSTR - 1);
        float v = (k < F_IN) ? W1[k * 16 + c] : 0.0f;
        wt[i] = (_Float16)v;
    }
}

// histogram + bucket scatter in one pass
__global__ __launch_bounds__(256) void k_scatter(const int* __restrict__ ei,
    int* cnt, int* bucket, int E, int N)
{
    int e = blockIdx.x * 256 + threadIdx.x;
    if (e < E) {
        int s = ei[e], d = ei[E + e];
        if ((unsigned)s < (unsigned)N && (unsigned)d < (unsigned)N) {
            int slot = atomicAdd(&cnt[d], 1);
            if (slot < BCAP) bucket[(size_t)d * BCAP + slot] = s;
        }
    }
}

// ---------------- layer-1 GEMM via MFMA: s1 = rsqrt(cnt+1) * (x @ W1) ----------------
// R15/R16 showed the 16-rows-per-wave pattern is stuck at ~3.4 TB/s: every chunk
// is a scattered 128B segment (row stride 5732B). Restructure: one BLOCK per
// 16-row tile; each wave streams 4 whole rows contiguously into an LDS fp16
// panel (pure streaming reads), then the 4 waves split K and MFMA from LDS,
// reducing partials through LDS at the end.
__global__ __launch_bounds__(256) void k_gemm(
    const float* __restrict__ x, const _Float16* __restrict__ wt,
    const int* __restrict__ cnt, float* __restrict__ s, int N)
{
    __shared__ _Float16 xs[16 * XSTR];   // 46336 B, zero-padded K to 1448
    __shared__ float red[4 * 256];       // 4096 B cross-wave reduce

    int tid = threadIdx.x;
    int w = tid >> 6, lane = tid & 63;
    int tile = blockIdx.x;
    int ntiles = (N + 15) >> 4;
    if (tile >= ntiles) return;

    struct __attribute__((packed, aligned(4))) f4u { float f[4]; };

    // ---- stage: wave w streams rows w*4 .. w*4+3 (contiguous along K) ----
    #pragma unroll
    for (int r = 0; r < 4; ++r) {
        int rr = w * 4 + r;                       // row within tile
        int grow = tile * 16 + rr;
        const float* xr = x + (size_t)((grow < N) ? grow : (N - 1)) * F_IN;
        #pragma unroll
        for (int it = 0; it < 6; ++it) {
            int k4 = it * 256 + lane * 4;
            if (k4 < XSTR) {
                _Float16 h4[4];
                if (k4 + 4 <= F_IN) {
                    f4u v = *(const f4u*)&xr[k4];
                    #pragma unroll
                    for (int j = 0; j < 4; ++j) h4[j] = (_Float16)v.f[j];
                } else {
                    #pragma unroll
                    for (int j = 0; j < 4; ++j) {
                        int k = k4 + j;
                        h4[j] = (_Float16)((k < F_IN) ? xr[k] : 0.0f);
                    }
                }
                *(__attribute__((ext_vector_type(4))) _Float16*)&xs[rr * XSTR + k4] =
                    *(__attribute__((ext_vector_type(4))) _Float16*)h4;
            }
        }
    }
    __syncthreads();

    // ---- compute: wave w takes chunks ch = w, w+4, ... (45 uniform chunks;
    //      LDS and wt are zero-padded so no tail guards) ----
    int rc = lane & 15;          // A-row within tile, and B/D column
    int g  = lane >> 4;          // k-group
    int kb = g * 8;
    const _Float16* wrow = wt + (rc << 11);
    const _Float16* xrow = xs + rc * XSTR;

    f32x4 acc = {0.0f, 0.0f, 0.0f, 0.0f};
    for (int ch = w; ch < 45; ch += 4) {
        int k0 = ch * 32 + kb;
        f16x8 av = *(const f16x8*)&xrow[k0];   // ds_read_b128, 2-way banks (free)
        f16x8 bv = *(const f16x8*)&wrow[k0];   // global, L2-hot
        acc = __builtin_amdgcn_mfma_f32_16x16x32_f16(av, bv, acc, 0, 0, 0);
    }

    // ---- reduce partials across the 4 waves ----
    // C/D: col = lane&15 (rc), row = g*4 + reg
    #pragma unroll
    for (int q = 0; q < 4; ++q)
        red[w * 256 + (g * 4 + q) * 16 + rc] = acc[q];
    __syncthreads();

    int row = tile * 16 + (tid >> 4);
    if (row < N) {
        float v = red[tid] + red[256 + tid] + red[512 + tid] + red[768 + tid];
        float di = rsqrtf((float)cnt[row] + 1.0f);
        s[row * 16 + (tid & 15)] = v * di;
    }
}

// ------- aggA: conv1-agg + b1 + relu + @W2 + dinv  (s1[16] -> s2[16]) -------
// one wave per dst; bucket row in regs, src via shfl; 8 gathers in flight per iter
__global__ __launch_bounds__(256) void k_aggA(
    const int* __restrict__ cnt, const int* __restrict__ bucket,
    const float* __restrict__ sin, const float* __restrict__ W,
    const float* __restrict__ bias, float* __restrict__ sout, int N)
{
    __shared__ float w[256], bs[16];
    int tid = threadIdx.x;
    w[tid] = W[tid];
    if (tid < 16) bs[tid] = bias[tid];
    __syncthreads();

    int wave = tid >> 6, lane = tid & 63;
    int dst = blockIdx.x * 4 + wave;
    if (dst >= N) return;
    int g = lane >> 4, c = lane & 15;
    int deg = min(cnt[dst], BCAP);
    const int* bk = bucket + (size_t)dst * BCAP;

    int e0 = (lane < deg)      ? bk[lane]      : 0;
    int e1 = (64 + lane < deg) ? bk[64 + lane] : 0;

    float acc = (g == 0) ? sin[dst * 16 + c] : 0.0f;     // self-loop
    for (int base = 0; base < deg; base += 32) {         // 8 gathers per iter
        float vs = 0.0f;
        #pragma unroll
        for (int i = 0; i < 8; ++i) {
            int j = base + g + 4 * i;
            int sa = __shfl(e0, j & 63, 64), sb = __shfl(e1, j & 63, 64);
            int sv = (j < 64) ? sa : sb;
            float v = (j < deg) ? sin[sv * 16 + c] : 0.0f;
            vs += v;
        }
        acc += vs;
    }
    acc += __shfl_xor(acc, 16, 64);
    acc += __shfl_xor(acc, 32, 64);

    float di = rsqrtf((float)cnt[dst] + 1.0f);
    float h = fmaxf(fmaf(di, acc, bs[c]), 0.0f);
    float t = 0.0f;
    #pragma unroll
    for (int k = 0; k < 16; ++k)
        t = fmaf(__shfl(h, k, 16), w[k * 16 + c], t);
    if (lane < 16) sout[dst * 16 + c] = di * t;
}

// ------- aggB: conv2-agg + b2 + relu + @W3 + dinv  (s2[16] -> s3[7]) -------
__global__ __launch_bounds__(256) void k_aggB(
    const int* __restrict__ cnt, const int* __restrict__ bucket,
    const float* __restrict__ sin, const float* __restrict__ W,
    const float* __restrict__ bias, float* __restrict__ sout, int N)
{
    __shared__ float w[112], bs[16];
    int tid = threadIdx.x;
    if (tid < 112) w[tid] = W[tid];
    if (tid < 16) bs[tid] = bias[tid];
    __syncthreads();

    int wave = tid >> 6, lane = tid & 63;
    int dst = blockIdx.x * 4 + wave;
    if (dst >= N) return;
    int g = lane >> 4, c = lane & 15;
    int deg = min(cnt[dst], BCAP);
    const int* bk = bucket + (size_t)dst * BCAP;

    int e0 = (lane < deg)      ? bk[lane]      : 0;
    int e1 = (64 + lane < deg) ? bk[64 + lane] : 0;

    float acc = (g == 0) ? sin[dst * 16 + c] : 0.0f;
    for (int base = 0; base < deg; base += 32) {
        float vs = 0.0f;
        #pragma unroll
        for (int i = 0; i < 8; ++i) {
            int j = base + g + 4 * i;
            int sa = __shfl(e0, j & 63, 64), sb = __shfl(e1, j & 63, 64);
            int sv = (j < 64) ? sa : sb;
            float v = (j < deg) ? sin[sv * 16 + c] : 0.0f;
            vs += v;
        }
        acc += vs;
    }
    acc += __shfl_xor(acc, 16, 64);
    acc += __shfl_xor(acc, 32, 64);

    float di = rsqrtf((float)cnt[dst] + 1.0f);
    float h = fmaxf(fmaf(di, acc, bs[c]), 0.0f);
    int cc = (c < 7) ? c : 0;
    float t = 0.0f;
    #pragma unroll
    for (int k = 0; k < 16; ++k)
        t = fmaf(__shfl(h, k, 16), w[k * 7 + cc], t);
    if (lane < 7) sout[dst * 7 + c] = di * t;
}

// ------- aggC: conv3-agg + b3 + log_softmax  (s3[7] -> out[7]) -------
__global__ __launch_bounds__(256) void k_aggC(
    const int* __restrict__ cnt, const int* __restrict__ bucket,
    const float* __restrict__ sin, const float* __restrict__ bias,
    float* __restrict__ out, int N)
{
    __shared__ float bs[8];
    int tid = threadIdx.x;
    if (tid < 7) bs[tid] = bias[tid];
    if (tid == 7) bs[7] = 0.0f;
    __syncthreads();

    int wave = tid >> 6, lane = tid & 63;
    int dst = blockIdx.x * 4 + wave;
    if (dst >= N) return;
    int g8 = lane >> 3, c8 = lane & 7;
    bool c7 = (c8 < 7);
    int cc = c7 ? c8 : 0;
    int deg = min(cnt[dst], BCAP);
    const int* bk = bucket + (size_t)dst * BCAP;

    int e0 = (lane < deg)      ? bk[lane]      : 0;
    int e1 = (64 + lane < deg) ? bk[64 + lane] : 0;

    float acc = (g8 == 0 && c7) ? sin[dst * 7 + c8] : 0.0f;
    for (int base = 0; base < deg; base += 64) {
        float vs = 0.0f;
        #pragma unroll
        for (int i = 0; i < 8; ++i) {
            int j = base + g8 + 8 * i;
            int sa = __shfl(e0, j & 63, 64), sb = __shfl(e1, j & 63, 64);
            int sv = (j < 64) ? sa : sb;
            float v = (j < deg && c7) ? sin[sv * 7 + cc] : 0.0f;
            vs += v;
        }
        acc += vs;
    }
    acc += __shfl_xor(acc, 8, 64);
    acc += __shfl_xor(acc, 16, 64);
    acc += __shfl_xor(acc, 32, 64);

    if (lane < 8) {
        float di = rsqrtf((float)cnt[dst] + 1.0f);
        float logit = c7 ? fmaf(di, acc, bs[c8]) : -1e30f;
        float m = logit;
        m = fmaxf(m, __shfl_xor(m, 1, 8));
        m = fmaxf(m, __shfl_xor(m, 2, 8));
        m = fmaxf(m, __shfl_xor(m, 4, 8));
        float e = c7 ? expf(logit - m) : 0.0f;
        float ssum = e;
        ssum += __shfl_xor(ssum, 1, 8);
        ssum += __shfl_xor(ssum, 2, 8);
        ssum += __shfl_xor(ssum, 4, 8);
        if (c7) out[dst * 7 + c8] = logit - m - logf(ssum);
    }
}

extern "C" void kernel_launch(void* const* d_in, const int* in_sizes, int n_in,
                              void* d_out, int out_size, void* d_ws, size_t ws_size,
                              hipStream_t stream)
{
    const float* x  = (const float*)d_in[0];
    const float* W1 = (const float*)d_in[1];
    const float* b1 = (const float*)d_in[2];
    const float* W2 = (const float*)d_in[3];
    const float* b2 = (const float*)d_in[4];
    const float* W3 = (const float*)d_in[5];
    const float* b3 = (const float*)d_in[6];
    const int*   ei = (const int*)d_in[7];
    float* out = (float*)d_out;

    int N = in_sizes[0] / F_IN;
    int E = in_sizes[7] / 2;

    int*      cnt    = (int*)d_ws;                           // N
    int*      bucket = cnt + N;                              // N*BCAP
    _Float16* wt     = (_Float16*)(bucket + (size_t)N * BCAP); // 16*WSTR halfs (64KB)
    float*    s1     = (float*)(wt + 16 * WSTR);             // 16N
    float*    s2     = s1 + 16 * (size_t)N;                  // 16N
    float*    s3     = s2 + 16 * (size_t)N;                  // 7N

    int nbN = (N + 255) / 256;
    int nbE = (E + 255) / 256;
    int nb4 = (N + 3) / 4;
    int ntiles = (N + 15) / 16;

    k_prep   <<<nbN, 256, 0, stream>>>(W1, cnt, wt, N);
    k_scatter<<<nbE, 256, 0, stream>>>(ei, cnt, bucket, E, N);
    k_gemm   <<<ntiles, 256, 0, stream>>>(x, wt, cnt, s1, N);
    k_aggA   <<<nb4, 256, 0, stream>>>(cnt, bucket, s1, W2, b1, s2, N);
    k_aggB   <<<nb4, 256, 0, stream>>>(cnt, bucket, s2, W3, b2, s3, N);
    k_aggC   <<<nb4, 256, 0, stream>>>(cnt, bucket, s3, b3, out, N);
}

// Round 18
// 509.967 us; speedup vs baseline: 1.0490x; 1.0490x over previous
//
#include <hip/hip_runtime.h>
#include <hip/hip_fp16.h>

#define F_IN 1433
#define BCAP 96        // bucket capacity; deg ~ Poisson(32), P(>96) ~ 1e-18
#define WSTR 2048      // wt row stride in halfs (global, L2-resident)
#define KPH  736       // K per stage phase (23 chunks of 32)
#define GRAN_PER_ROW (KPH / 4)        // 184 16B-granules per row
#define GRAN_TOTAL   (16 * GRAN_PER_ROW)  // 2944 per phase

// edge_index int32: src = ei[0:E], dst = ei[E:2E]

typedef _Float16 f16x8 __attribute__((ext_vector_type(8)));
typedef float    f32x4 __attribute__((ext_vector_type(4)));
typedef __attribute__((address_space(1))) const unsigned int gu32;
typedef __attribute__((address_space(3))) unsigned int lu32;

// zero cnt + build fp16 W^T table (wt[c][k], zero-padded) in one node
__global__ __launch_bounds__(256) void k_prep(const float* __restrict__ W1,
    int* __restrict__ cnt, _Float16* __restrict__ wt, int N)
{
    int i = blockIdx.x * 256 + threadIdx.x;
    if (i < N) cnt[i] = 0;
    if (i < 16 * WSTR) {
        int c = i >> 11, k = i & (WSTR - 1);
        float v = (k < F_IN) ? W1[k * 16 + c] : 0.0f;
        wt[i] = (_Float16)v;
    }
}

// histogram + bucket scatter in one pass
__global__ __launch_bounds__(256) void k_scatter(const int* __restrict__ ei,
    int* cnt, int* bucket, int E, int N)
{
    int e = blockIdx.x * 256 + threadIdx.x;
    if (e < E) {
        int s = ei[e], d = ei[E + e];
        if ((unsigned)s < (unsigned)N && (unsigned)d < (unsigned)N) {
            int slot = atomicAdd(&cnt[d], 1);
            if (slot < BCAP) bucket[(size_t)d * BCAP + slot] = s;
        }
    }
}

// ---------------- layer-1 GEMM via MFMA: s1 = rsqrt(cnt+1) * (x @ W1) ----------------
// R15-R17: every x path through VGPRs gets serialized by the compiler (warm reps
// = cold reps, VGPR=24). Fix per guide Common-mistake #1: DMA x straight to LDS
// with global_load_lds (width 16, no VGPR dest, loads stay in flight until one
// barrier drain). One block per 16-row tile; fp32 panel xs[16][736], 2 K-phases;
// 4 waves split chunks, cross-wave LDS reduce.
__global__ __launch_bounds__(256) void k_gemm(
    const float* __restrict__ x, const _Float16* __restrict__ wt,
    const int* __restrict__ cnt, float* __restrict__ s, int N)
{
    __shared__ float xs[16 * KPH];       // 47104 B
    __shared__ float red[4 * 256];       // 4096 B

    int tid = threadIdx.x;
    int w = tid >> 6, lane = tid & 63;
    int tile = blockIdx.x;
    int ntiles = (N + 15) >> 4;
    if (tile >= ntiles) return;

    f32x4 acc = {0.0f, 0.0f, 0.0f, 0.0f};
    int rc = lane & 15;          // A-row within tile, and B/D column
    int g  = lane >> 4;          // k-group
    const _Float16* wrow = wt + (rc << 11);
    const float* xrow = xs + rc * KPH;

    for (int p = 0; p < 2; ++p) {
        // ---- stage phase p: DMA granules (LDS linear, per-lane global src) ----
        for (int i = 0; i < 12; ++i) {
            int G = i * 256 + tid;
            if (G < GRAN_TOTAL) {                     // last iter: waves 0,1 only
                int row = G / GRAN_PER_ROW;
                int kloc = (G - row * GRAN_PER_ROW) * 4;
                int kglob = p * KPH + kloc;
                int grow = tile * 16 + row;
                if (grow >= N) grow = N - 1;
                if (kglob + 3 <= F_IN - 1) {          // always true for p=0
                    const float* gp = x + (size_t)grow * F_IN + kglob;
                    __builtin_amdgcn_global_load_lds(
                        (gu32*)gp, (lu32*)&xs[G * 4], 16, 0, 0);
                }
            }
        }
        if (p == 1 && tid < 16) {
            // fixup row tid: k=1432 value + zero-pad kloc 697..735
            int grow = tile * 16 + tid;
            if (grow >= N) grow = N - 1;
            float val = x[(size_t)grow * F_IN + (F_IN - 1)];
            float* dst = xs + tid * KPH + 696;        // kglob 1432..1435
            f32x4 z0 = {val, 0.0f, 0.0f, 0.0f};
            *(f32x4*)dst = z0;
            f32x4 zz = {0.0f, 0.0f, 0.0f, 0.0f};
            #pragma unroll
            for (int j = 1; j < 10; ++j)              // kloc 700..735
                *(f32x4*)(dst + 4 * j) = zz;
        }
        __syncthreads();                              // drains DMA (vmcnt) + ds_writes

        // ---- compute phase p: wave w takes chunks ch = w, w+4, ... of 23 ----
        for (int ch = w; ch < 23; ch += 4) {
            int kloc = ch * 32 + g * 8;
            f32x4 xa = *(const f32x4*)&xrow[kloc];
            f32x4 xb = *(const f32x4*)&xrow[kloc + 4];
            f16x8 bv = *(const f16x8*)&wrow[p * KPH + kloc];   // L2-hot
            f16x8 av;
            #pragma unroll
            for (int j = 0; j < 4; ++j) {
                av[j]     = (_Float16)xa[j];
                av[j + 4] = (_Float16)xb[j];
            }
            acc = __builtin_amdgcn_mfma_f32_16x16x32_f16(av, bv, acc, 0, 0, 0);
        }
        __syncthreads();                              // reads done before next stage
    }

    // ---- reduce partials across the 4 waves ----
    // C/D: col = lane&15 (rc), row = g*4 + reg
    #pragma unroll
    for (int q = 0; q < 4; ++q)
        red[w * 256 + (g * 4 + q) * 16 + rc] = acc[q];
    __syncthreads();

    int row = tile * 16 + (tid >> 4);
    if (row < N) {
        float v = red[tid] + red[256 + tid] + red[512 + tid] + red[768 + tid];
        float di = rsqrtf((float)cnt[row] + 1.0f);
        s[row * 16 + (tid & 15)] = v * di;
    }
}

// ------- aggA: conv1-agg + b1 + relu + @W2 + dinv  (s1[16] -> s2[16]) -------
// one wave per dst; bucket row in regs, src via shfl; 8 gathers in flight per iter
__global__ __launch_bounds__(256) void k_aggA(
    const int* __restrict__ cnt, const int* __restrict__ bucket,
    const float* __restrict__ sin, const float* __restrict__ W,
    const float* __restrict__ bias, float* __restrict__ sout, int N)
{
    __shared__ float w[256], bs[16];
    int tid = threadIdx.x;
    w[tid] = W[tid];
    if (tid < 16) bs[tid] = bias[tid];
    __syncthreads();

    int wave = tid >> 6, lane = tid & 63;
    int dst = blockIdx.x * 4 + wave;
    if (dst >= N) return;
    int g = lane >> 4, c = lane & 15;
    int deg = min(cnt[dst], BCAP);
    const int* bk = bucket + (size_t)dst * BCAP;

    int e0 = (lane < deg)      ? bk[lane]      : 0;
    int e1 = (64 + lane < deg) ? bk[64 + lane] : 0;

    float acc = (g == 0) ? sin[dst * 16 + c] : 0.0f;     // self-loop
    for (int base = 0; base < deg; base += 32) {         // 8 gathers per iter
        float vs = 0.0f;
        #pragma unroll
        for (int i = 0; i < 8; ++i) {
            int j = base + g + 4 * i;
            int sa = __shfl(e0, j & 63, 64), sb = __shfl(e1, j & 63, 64);
            int sv = (j < 64) ? sa : sb;
            float v = (j < deg) ? sin[sv * 16 + c] : 0.0f;
            vs += v;
        }
        acc += vs;
    }
    acc += __shfl_xor(acc, 16, 64);
    acc += __shfl_xor(acc, 32, 64);

    float di = rsqrtf((float)cnt[dst] + 1.0f);
    float h = fmaxf(fmaf(di, acc, bs[c]), 0.0f);
    float t = 0.0f;
    #pragma unroll
    for (int k = 0; k < 16; ++k)
        t = fmaf(__shfl(h, k, 16), w[k * 16 + c], t);
    if (lane < 16) sout[dst * 16 + c] = di * t;
}

// ------- aggB: conv2-agg + b2 + relu + @W3 + dinv  (s2[16] -> s3[7]) -------
__global__ __launch_bounds__(256) void k_aggB(
    const int* __restrict__ cnt, const int* __restrict__ bucket,
    const float* __restrict__ sin, const float* __restrict__ W,
    const float* __restrict__ bias, float* __restrict__ sout, int N)
{
    __shared__ float w[112], bs[16];
    int tid = threadIdx.x;
    if (tid < 112) w[tid] = W[tid];
    if (tid < 16) bs[tid] = bias[tid];
    __syncthreads();

    int wave = tid >> 6, lane = tid & 63;
    int dst = blockIdx.x * 4 + wave;
    if (dst >= N) return;
    int g = lane >> 4, c = lane & 15;
    int deg = min(cnt[dst], BCAP);
    const int* bk = bucket + (size_t)dst * BCAP;

    int e0 = (lane < deg)      ? bk[lane]      : 0;
    int e1 = (64 + lane < deg) ? bk[64 + lane] : 0;

    float acc = (g == 0) ? sin[dst * 16 + c] : 0.0f;
    for (int base = 0; base < deg; base += 32) {
        float vs = 0.0f;
        #pragma unroll
        for (int i = 0; i < 8; ++i) {
            int j = base + g + 4 * i;
            int sa = __shfl(e0, j & 63, 64), sb = __shfl(e1, j & 63, 64);
            int sv = (j < 64) ? sa : sb;
            float v = (j < deg) ? sin[sv * 16 + c] : 0.0f;
            vs += v;
        }
        acc += vs;
    }
    acc += __shfl_xor(acc, 16, 64);
    acc += __shfl_xor(acc, 32, 64);

    float di = rsqrtf((float)cnt[dst] + 1.0f);
    float h = fmaxf(fmaf(di, acc, bs[c]), 0.0f);
    int cc = (c < 7) ? c : 0;
    float t = 0.0f;
    #pragma unroll
    for (int k = 0; k < 16; ++k)
        t = fmaf(__shfl(h, k, 16), w[k * 7 + cc], t);
    if (lane < 7) sout[dst * 7 + c] = di * t;
}

// ------- aggC: conv3-agg + b3 + log_softmax  (s3[7] -> out[7]) -------
__global__ __launch_bounds__(256) void k_aggC(
    const int* __restrict__ cnt, const int* __restrict__ bucket,
    const float* __restrict__ sin, const float* __restrict__ bias,
    float* __restrict__ out, int N)
{
    __shared__ float bs[8];
    int tid = threadIdx.x;
    if (tid < 7) bs[tid] = bias[tid];
    if (tid == 7) bs[7] = 0.0f;
    __syncthreads();

    int wave = tid >> 6, lane = tid & 63;
    int dst = blockIdx.x * 4 + wave;
    if (dst >= N) return;
    int g8 = lane >> 3, c8 = lane & 7;
    bool c7 = (c8 < 7);
    int cc = c7 ? c8 : 0;
    int deg = min(cnt[dst], BCAP);
    const int* bk = bucket + (size_t)dst * BCAP;

    int e0 = (lane < deg)      ? bk[lane]      : 0;
    int e1 = (64 + lane < deg) ? bk[64 + lane] : 0;

    float acc = (g8 == 0 && c7) ? sin[dst * 7 + c8] : 0.0f;
    for (int base = 0; base < deg; base += 64) {
        float vs = 0.0f;
        #pragma unroll
        for (int i = 0; i < 8; ++i) {
            int j = base + g8 + 8 * i;
            int sa = __shfl(e0, j & 63, 64), sb = __shfl(e1, j & 63, 64);
            int sv = (j < 64) ? sa : sb;
            float v = (j < deg && c7) ? sin[sv * 7 + cc] : 0.0f;
            vs += v;
        }
        acc += vs;
    }
    acc += __shfl_xor(acc, 8, 64);
    acc += __shfl_xor(acc, 16, 64);
    acc += __shfl_xor(acc, 32, 64);

    if (lane < 8) {
        float di = rsqrtf((float)cnt[dst] + 1.0f);
        float logit = c7 ? fmaf(di, acc, bs[c8]) : -1e30f;
        float m = logit;
        m = fmaxf(m, __shfl_xor(m, 1, 8));
        m = fmaxf(m, __shfl_xor(m, 2, 8));
        m = fmaxf(m, __shfl_xor(m, 4, 8));
        float e = c7 ? expf(logit - m) : 0.0f;
        float ssum = e;
        ssum += __shfl_xor(ssum, 1, 8);
        ssum += __shfl_xor(ssum, 2, 8);
        ssum += __shfl_xor(ssum, 4, 8);
        if (c7) out[dst * 7 + c8] = logit - m - logf(ssum);
    }
}

extern "C" void kernel_launch(void* const* d_in, const int* in_sizes, int n_in,
                              void* d_out, int out_size, void* d_ws, size_t ws_size,
                              hipStream_t stream)
{
    const float* x  = (const float*)d_in[0];
    const float* W1 = (const float*)d_in[1];
    const float* b1 = (const float*)d_in[2];
    const float* W2 = (const float*)d_in[3];
    const float* b2 = (const float*)d_in[4];
    const float* W3 = (const float*)d_in[5];
    const float* b3 = (const float*)d_in[6];
    const int*   ei = (const int*)d_in[7];
    float* out = (float*)d_out;

    int N = in_sizes[0] / F_IN;
    int E = in_sizes[7] / 2;

    int*      cnt    = (int*)d_ws;                           // N
    int*      bucket = cnt + N;                              // N*BCAP
    _Float16* wt     = (_Float16*)(bucket + (size_t)N * BCAP); // 16*WSTR halfs (64KB)
    float*    s1     = (float*)(wt + 16 * WSTR);             // 16N
    float*    s2     = s1 + 16 * (size_t)N;                  // 16N
    float*    s3     = s2 + 16 * (size_t)N;                  // 7N

    int nbN = (N + 255) / 256;
    int nbE = (E + 255) / 256;
    int nb4 = (N + 3) / 4;
    int ntiles = (N + 15) / 16;

    k_prep   <<<nbN, 256, 0, stream>>>(W1, cnt, wt, N);
    k_scatter<<<nbE, 256, 0, stream>>>(ei, cnt, bucket, E, N);
    k_gemm   <<<ntiles, 256, 0, stream>>>(x, wt, cnt, s1, N);
    k_aggA   <<<nb4, 256, 0, stream>>>(cnt, bucket, s1, W2, b1, s2, N);
    k_aggB   <<<nb4, 256, 0, stream>>>(cnt, bucket, s2, W3, b2, s3, N);
    k_aggC   <<<nb4, 256, 0, stream>>>(cnt, bucket, s3, b3, out, N);
}

// Round 19
// 509.161 us; speedup vs baseline: 1.0507x; 1.0016x over previous
//
#include <hip/hip_runtime.h>
#include <hip/hip_fp16.h>

#define F_IN 1433
#define BCAP 96        // bucket capacity; deg ~ Poisson(32), P(>96) ~ 1e-18
#define WSTR 2048      // wt row stride in halfs (global, L2-resident)

// edge_index int32: src = ei[0:E], dst = ei[E:2E]

typedef _Float16 f16x8 __attribute__((ext_vector_type(8)));
typedef float    f32x4 __attribute__((ext_vector_type(4)));

// zero cnt + build fp16 W^T table (wt[c][k], zero-padded) in one node
__global__ __launch_bounds__(256) void k_prep(const float* __restrict__ W1,
    int* __restrict__ cnt, _Float16* __restrict__ wt, int N)
{
    int i = blockIdx.x * 256 + threadIdx.x;
    if (i < N) cnt[i] = 0;
    if (i < 16 * WSTR) {
        int c = i >> 11, k = i & (WSTR - 1);
        float v = (k < F_IN) ? W1[k * 16 + c] : 0.0f;
        wt[i] = (_Float16)v;
    }
}

// ---- merged node: blocks [0, nbG) = gemm (RAW g1 = x@W1); rest = scatter ----
// gemm and scatter are independent (gemm no longer reads cnt); scatter's
// L2-atomic traffic overlaps gemm's HBM stream instead of serializing after it.
__global__ __launch_bounds__(256) void k_ms(
    const float* __restrict__ x, const _Float16* __restrict__ wt,
    const int* __restrict__ ei, int* __restrict__ cnt, int* __restrict__ bucket,
    float* __restrict__ g1, int nbG, int N, int E)
{
    int tid = threadIdx.x;
    if ((int)blockIdx.x < nbG) {
        // ---------- gemm path (R12 structure, raw output) ----------
        int wv = tid >> 6, lane = tid & 63;
        int ntiles = (N + 15) >> 4;
        int tile = blockIdx.x * 4 + wv;
        if (tile >= ntiles) return;

        int rc = lane & 15;          // A-row within tile, and B/D column
        int g  = lane >> 4;          // k-group
        int row = tile * 16 + rc;
        const float* xr = x + (size_t)((row < N) ? row : (N - 1)) * F_IN;
        const _Float16* wrow = wt + (rc << 11);

        struct __attribute__((packed, aligned(4))) f4u { float f[4]; };

        f32x4 acc = {0.0f, 0.0f, 0.0f, 0.0f};
        int kb = g * 8;

        #pragma unroll 4
        for (int ch = 0; ch < 44; ++ch) {       // full chunks: k0 = ch*32 + g*8
            int k0 = ch * 32 + kb;
            f4u xa = *(const f4u*)&xr[k0];
            f4u xb = *(const f4u*)&xr[k0 + 4];
            f16x8 bv = *(const f16x8*)&wrow[k0];   // global, L2-hot
            f16x8 av;
            #pragma unroll
            for (int j = 0; j < 4; ++j) {
                av[j]     = (_Float16)xa.f[j];
                av[j + 4] = (_Float16)xb.f[j];
            }
            acc = __builtin_amdgcn_mfma_f32_16x16x32_f16(av, bv, acc, 0, 0, 0);
        }
        {   // tail chunk: k0 = 1408 + g*8, guarded
            int k0 = 1408 + kb;
            f16x8 av, bv;
            bv = *(const f16x8*)&wrow[k0];      // table zero-padded
            #pragma unroll
            for (int j = 0; j < 8; ++j) {
                int k = k0 + j;
                av[j] = (_Float16)((k < F_IN) ? xr[k] : 0.0f);
            }
            acc = __builtin_amdgcn_mfma_f32_16x16x32_f16(av, bv, acc, 0, 0, 0);
        }

        #pragma unroll
        for (int r = 0; r < 4; ++r) {           // C/D: col=lane&15, row=(lane>>4)*4+reg
            int grow = tile * 16 + g * 4 + r;
            if (grow < N) g1[grow * 16 + rc] = acc[r];   // RAW (dinv in aggA)
        }
    } else {
        // ---------- scatter path: histogram + bucket, 1 edge/thread ----------
        int e = ((int)blockIdx.x - nbG) * 256 + tid;
        if (e < E) {
            int s = ei[e], d = ei[E + e];
            if ((unsigned)s < (unsigned)N && (unsigned)d < (unsigned)N) {
                int slot = atomicAdd(&cnt[d], 1);
                if (slot < BCAP) bucket[(size_t)d * BCAP + slot] = s;
            }
        }
    }
}

// ------- aggA: conv1-agg (dinv[src] per edge) + b1 + relu + @W2 + dinv -------
// 16 dsts per block (4 per wave), weights staged once; 8 gathers in flight
__global__ __launch_bounds__(256) void k_aggA(
    const int* __restrict__ cnt, const int* __restrict__ bucket,
    const float* __restrict__ g1, const float* __restrict__ W,
    const float* __restrict__ bias, float* __restrict__ sout, int N)
{
    __shared__ float w[256], bs[16];
    int tid = threadIdx.x;
    w[tid] = W[tid];
    if (tid < 16) bs[tid] = bias[tid];
    __syncthreads();

    int wave = tid >> 6, lane = tid & 63;
    int g = lane >> 4, c = lane & 15;
    int base0 = blockIdx.x * 16 + wave * 4;

    for (int it = 0; it < 4; ++it) {
        int dst = base0 + it;
        if (dst >= N) break;
        int cd = cnt[dst];
        int deg = min(cd, BCAP);
        float di = rsqrtf((float)cd + 1.0f);
        const int* bk = bucket + (size_t)dst * BCAP;

        int e0 = (lane < deg)      ? bk[lane]      : 0;
        int e1 = (64 + lane < deg) ? bk[64 + lane] : 0;

        float acc = (g == 0) ? di * g1[dst * 16 + c] : 0.0f;   // self-loop
        for (int base = 0; base < deg; base += 32) {           // 8 gathers/iter
            float vs = 0.0f;
            #pragma unroll
            for (int i = 0; i < 8; ++i) {
                int j = base + g + 4 * i;
                int sa = __shfl(e0, j & 63, 64), sb = __shfl(e1, j & 63, 64);
                int sv = (j < 64) ? sa : sb;
                float v = 0.0f;
                if (j < deg)
                    v = rsqrtf((float)cnt[sv] + 1.0f) * g1[sv * 16 + c];
                vs += v;
            }
            acc += vs;
        }
        acc += __shfl_xor(acc, 16, 64);
        acc += __shfl_xor(acc, 32, 64);

        float h = fmaxf(fmaf(di, acc, bs[c]), 0.0f);
        float t = 0.0f;
        #pragma unroll
        for (int k = 0; k < 16; ++k)
            t = fmaf(__shfl(h, k, 16), w[k * 16 + c], t);
        if (lane < 16) sout[dst * 16 + c] = di * t;
    }
}

// ------- aggB: conv2-agg + b2 + relu + @W3 + dinv  (s2[16] -> s3[7]) -------
__global__ __launch_bounds__(256) void k_aggB(
    const int* __restrict__ cnt, const int* __restrict__ bucket,
    const float* __restrict__ sin, const float* __restrict__ W,
    const float* __restrict__ bias, float* __restrict__ sout, int N)
{
    __shared__ float w[112], bs[16];
    int tid = threadIdx.x;
    if (tid < 112) w[tid] = W[tid];
    if (tid < 16) bs[tid] = bias[tid];
    __syncthreads();

    int wave = tid >> 6, lane = tid & 63;
    int g = lane >> 4, c = lane & 15;
    int base0 = blockIdx.x * 16 + wave * 4;

    for (int it = 0; it < 4; ++it) {
        int dst = base0 + it;
        if (dst >= N) break;
        int cd = cnt[dst];
        int deg = min(cd, BCAP);
        float di = rsqrtf((float)cd + 1.0f);
        const int* bk = bucket + (size_t)dst * BCAP;

        int e0 = (lane < deg)      ? bk[lane]      : 0;
        int e1 = (64 + lane < deg) ? bk[64 + lane] : 0;

        float acc = (g == 0) ? sin[dst * 16 + c] : 0.0f;
        for (int base = 0; base < deg; base += 32) {
            float vs = 0.0f;
            #pragma unroll
            for (int i = 0; i < 8; ++i) {
                int j = base + g + 4 * i;
                int sa = __shfl(e0, j & 63, 64), sb = __shfl(e1, j & 63, 64);
                int sv = (j < 64) ? sa : sb;
                float v = (j < deg) ? sin[sv * 16 + c] : 0.0f;
                vs += v;
            }
            acc += vs;
        }
        acc += __shfl_xor(acc, 16, 64);
        acc += __shfl_xor(acc, 32, 64);

        float h = fmaxf(fmaf(di, acc, bs[c]), 0.0f);
        int cc = (c < 7) ? c : 0;
        float t = 0.0f;
        #pragma unroll
        for (int k = 0; k < 16; ++k)
            t = fmaf(__shfl(h, k, 16), w[k * 7 + cc], t);
        if (lane < 7) sout[dst * 7 + c] = di * t;
    }
}

// ------- aggC: conv3-agg + b3 + log_softmax  (s3[7] -> out[7]) -------
__global__ __launch_bounds__(256) void k_aggC(
    const int* __restrict__ cnt, const int* __restrict__ bucket,
    const float* __restrict__ sin, const float* __restrict__ bias,
    float* __restrict__ out, int N)
{
    __shared__ float bs[8];
    int tid = threadIdx.x;
    if (tid < 7) bs[tid] = bias[tid];
    if (tid == 7) bs[7] = 0.0f;
    __syncthreads();

    int wave = tid >> 6, lane = tid & 63;
    int g8 = lane >> 3, c8 = lane & 7;
    bool c7 = (c8 < 7);
    int cc = c7 ? c8 : 0;
    int base0 = blockIdx.x * 16 + wave * 4;

    for (int it = 0; it < 4; ++it) {
        int dst = base0 + it;
        if (dst >= N) break;
        int cd = cnt[dst];
        int deg = min(cd, BCAP);
        float di = rsqrtf((float)cd + 1.0f);
        const int* bk = bucket + (size_t)dst * BCAP;

        int e0 = (lane < deg)      ? bk[lane]      : 0;
        int e1 = (64 + lane < deg) ? bk[64 + lane] : 0;

        float acc = (g8 == 0 && c7) ? sin[dst * 7 + c8] : 0.0f;
        for (int base = 0; base < deg; base += 64) {
            float vs = 0.0f;
            #pragma unroll
            for (int i = 0; i < 8; ++i) {
                int j = base + g8 + 8 * i;
                int sa = __shfl(e0, j & 63, 64), sb = __shfl(e1, j & 63, 64);
                int sv = (j < 64) ? sa : sb;
                float v = (j < deg && c7) ? sin[sv * 7 + cc] : 0.0f;
                vs += v;
            }
            acc += vs;
        }
        acc += __shfl_xor(acc, 8, 64);
        acc += __shfl_xor(acc, 16, 64);
        acc += __shfl_xor(acc, 32, 64);

        if (lane < 8) {
            float logit = c7 ? fmaf(di, acc, bs[c8]) : -1e30f;
            float m = logit;
            m = fmaxf(m, __shfl_xor(m, 1, 8));
            m = fmaxf(m, __shfl_xor(m, 2, 8));
            m = fmaxf(m, __shfl_xor(m, 4, 8));
            float e = c7 ? expf(logit - m) : 0.0f;
            float ssum = e;
            ssum += __shfl_xor(ssum, 1, 8);
            ssum += __shfl_xor(ssum, 2, 8);
            ssum += __shfl_xor(ssum, 4, 8);
            if (c7) out[dst * 7 + c8] = logit - m - logf(ssum);
        }
    }
}

extern "C" void kernel_launch(void* const* d_in, const int* in_sizes, int n_in,
                              void* d_out, int out_size, void* d_ws, size_t ws_size,
                              hipStream_t stream)
{
    const float* x  = (const float*)d_in[0];
    const float* W1 = (const float*)d_in[1];
    const float* b1 = (const float*)d_in[2];
    const float* W2 = (const float*)d_in[3];
    const float* b2 = (const float*)d_in[4];
    const float* W3 = (const float*)d_in[5];
    const float* b3 = (const float*)d_in[6];
    const int*   ei = (const int*)d_in[7];
    float* out = (float*)d_out;

    int N = in_sizes[0] / F_IN;
    int E = in_sizes[7] / 2;

    int*      cnt    = (int*)d_ws;                           // N
    int*      bucket = cnt + N;                              // N*BCAP
    _Float16* wt     = (_Float16*)(bucket + (size_t)N * BCAP); // 16*WSTR halfs (64KB)
    float*    g1     = (float*)(wt + 16 * WSTR);             // 16N (raw x@W1)
    float*    s2     = g1 + 16 * (size_t)N;                  // 16N
    float*    s3     = s2 + 16 * (size_t)N;                  // 7N

    int nbN  = (N + 255) / 256;
    int nbE  = (E + 255) / 256;
    int nb16 = (N + 15) / 16;
    int ntiles = (N + 15) / 16;
    int nbG  = (ntiles + 3) / 4;

    k_prep<<<nbN, 256, 0, stream>>>(W1, cnt, wt, N);
    k_ms  <<<nbG + nbE, 256, 0, stream>>>(x, wt, ei, cnt, bucket, g1, nbG, N, E);
    k_aggA<<<nb16, 256, 0, stream>>>(cnt, bucket, g1, W2, b1, s2, N);
    k_aggB<<<nb16, 256, 0, stream>>>(cnt, bucket, s2, W3, b2, s3, N);
    k_aggC<<<nb16, 256, 0, stream>>>(cnt, bucket, s3, b3, out, N);
}